// Round 7
// baseline (145.669 us; speedup 1.0000x reference)
//
#include <hip/hip_runtime.h>
#include <hip/hip_bf16.h>

// Guided attention loss, fused single-kernel version.
//   guided(b,x,y) = 1 - exp(-(y/il - x/ol)^2 / (2*sigma^2)),  sigma=0.4
//   out[b]   = sum(guided*att over valid) / ol
//   out[B+b] = sum((guided*att)^2 over valid) / ol
// Shapes fixed: B=64, T_out=2048, T_in=512.
//
// Round 7: fuse the final reduction via last-block ticket (device-scope
// atomicAdd + __threadfence), removing the second kernel node and the
// k1-tail -> k2-launch drain. Ticket zeroed per call by a 4-byte
// hipMemsetAsync (memset node in the captured graph).

#define GA_B     64
#define GA_TOUT  2048
#define GA_TIN   512
#define ROWS_PER_WAVE   8
#define WAVES_PER_BLOCK 4
#define ROWS_PER_BLOCK  (ROWS_PER_WAVE * WAVES_PER_BLOCK)   // 32
#define BLOCK_THREADS   256
#define GRID_X          (GA_TOUT / ROWS_PER_BLOCK)           // 64
#define NBLOCKS         (GRID_X * GA_B)                      // 4096
// KS = sqrt(3.125 * log2(e)):  2^(-(KS*z)^2) = exp(-z^2 * 3.125)
#define KS 2.1233046f

__global__ __launch_bounds__(BLOCK_THREADS)
void ga_fused_kernel(const float* __restrict__ att,
                     const int* __restrict__ ilens,
                     const int* __restrict__ olens,
                     float2* __restrict__ part,       // [GA_B * GRID_X]
                     unsigned int* __restrict__ ticket,
                     float* __restrict__ out) {
    const int b    = blockIdx.y;
    const int lane = threadIdx.x & 63;
    const int wave = threadIdx.x >> 6;
    const int waveRow = blockIdx.x * ROWS_PER_BLOCK + wave * ROWS_PER_WAVE;

    const int ol = olens[b];
    const int il = ilens[b];
    const int nv = (il + 3) >> 2;            // float4 chunks per row, <= 128

    float l1 = 0.0f, l2 = 0.0f;

    if (waveRow < ol) {
        const float inv_il_s = KS / (float)il;
        const float inv_ol_s = KS / (float)ol;
        const bool  hi       = (nv > 64);     // any of cols 256..511 valid?
        const float4* __restrict__ base =
            (const float4*)(att + (size_t)b * GA_TOUT * GA_TIN);

        float ys0[4], ys1[4], m0[4], m1[4];
        #pragma unroll
        for (int j = 0; j < 4; ++j) {
            const int y0 = (lane << 2) + j;
            const int y1 = y0 + 256;
            ys0[j] = (float)y0 * inv_il_s;
            ys1[j] = (float)y1 * inv_il_s;
            m0[j]  = (y0 < il) ? 1.0f : 0.0f;
            m1[j]  = (y1 < il) ? 1.0f : 0.0f;
        }

        float4 A0[ROWS_PER_WAVE], A1[ROWS_PER_WAVE];
        #pragma unroll
        for (int r = 0; r < ROWS_PER_WAVE; ++r) {
            A0[r] = make_float4(0.f, 0.f, 0.f, 0.f);
            A1[r] = make_float4(0.f, 0.f, 0.f, 0.f);
            const int x = waveRow + r;
            if (x < ol) {
                const float4* __restrict__ rowp = base + (size_t)x * (GA_TIN / 4);
                if (lane < nv)              A0[r] = rowp[lane];
                if (hi && (lane + 64 < nv)) A1[r] = rowp[lane + 64];
            }
        }

        #pragma unroll
        for (int r = 0; r < ROWS_PER_WAVE; ++r) {
            const int   x   = waveRow + r;
            const float gxs = (float)x * inv_ol_s;
            {
                const float4 a = A0[r];
                #pragma unroll
                for (int j = 0; j < 4; ++j) {
                    const float av = (j == 0) ? a.x : (j == 1) ? a.y
                                   : (j == 2) ? a.z : a.w;
                    const float w  = ys0[j] - gxs;
                    const float E  = exp2f(-w * w);
                    const float q  = av - av * E;       // guided * att
                    const float e  = q * m0[j];
                    l1 += e;
                    l2 += e * e;
                }
            }
            if (hi) {
                const float4 a = A1[r];
                #pragma unroll
                for (int j = 0; j < 4; ++j) {
                    const float av = (j == 0) ? a.x : (j == 1) ? a.y
                                   : (j == 2) ? a.z : a.w;
                    const float w  = ys1[j] - gxs;
                    const float E  = exp2f(-w * w);
                    const float q  = av - av * E;
                    const float e  = q * m1[j];
                    l1 += e;
                    l2 += e * e;
                }
            }
        }
    }

    // ---- block reduce (4 waves) ----
    #pragma unroll
    for (int o = 32; o > 0; o >>= 1) {
        l1 += __shfl_down(l1, o, 64);
        l2 += __shfl_down(l2, o, 64);
    }
    __shared__ float s1[WAVES_PER_BLOCK];
    __shared__ float s2[WAVES_PER_BLOCK];
    __shared__ int   s_last;
    if (lane == 0) { s1[wave] = l1; s2[wave] = l2; }
    __syncthreads();
    if (threadIdx.x == 0) {
        const float b1 = s1[0] + s1[1] + s1[2] + s1[3];
        const float b2 = s2[0] + s2[1] + s2[2] + s2[3];
        part[b * GRID_X + blockIdx.x] = make_float2(b1, b2);
        __threadfence();                            // release partial
        const unsigned int old = atomicAdd(ticket, 1u);
        s_last = (old == NBLOCKS - 1) ? 1 : 0;
    }
    __syncthreads();
    if (s_last == 0) return;

    // ---- last block: final reduction over all partials ----
    __threadfence();                                // acquire partials
    const int t  = threadIdx.x;
    const int bb = t >> 2;                          // batch, 4 threads each
    const int q  = t & 3;
    float f1 = 0.0f, f2 = 0.0f;
    #pragma unroll
    for (int c = 0; c < GRID_X / 4; ++c) {
        const float2 v = part[bb * GRID_X + q * (GRID_X / 4) + c];
        f1 += v.x; f2 += v.y;
    }
    f1 += __shfl_down(f1, 2, 4);  f2 += __shfl_down(f2, 2, 4);
    f1 += __shfl_down(f1, 1, 4);  f2 += __shfl_down(f2, 1, 4);
    if (q == 0) {
        const float d = (float)olens[bb];
        out[bb]        = f1 / d;
        out[GA_B + bb] = f2 / d;
    }
}

extern "C" void kernel_launch(void* const* d_in, const int* in_sizes, int n_in,
                              void* d_out, int out_size, void* d_ws, size_t ws_size,
                              hipStream_t stream) {
    const float* att   = (const float*)d_in[0];
    const int*   ilens = (const int*)d_in[1];
    const int*   olens = (const int*)d_in[2];
    float*       out   = (float*)d_out;

    unsigned int* ticket = (unsigned int*)d_ws;                   // 4 B @ 0
    float2*       part   = (float2*)((char*)d_ws + 256);          // 32 KB

    hipMemsetAsync(ticket, 0, sizeof(unsigned int), stream);
    dim3 grid(GRID_X, GA_B);
    ga_fused_kernel<<<grid, BLOCK_THREADS, 0, stream>>>(att, ilens, olens,
                                                        part, ticket, out);
}

// Round 8
// 34.676 us; speedup vs baseline: 4.2009x; 4.2009x over previous
//
#include <hip/hip_runtime.h>
#include <hip/hip_bf16.h>

// Guided attention loss, single kernel + per-batch float atomics.
//   guided(b,x,y) = 1 - exp(-(y/il - x/ol)^2 / (2*sigma^2)),  sigma=0.4
//   out[b]   = sum(guided*att over valid) / ol
//   out[B+b] = sum((guided*att)^2 over valid) / ol
// Shapes fixed: B=64, T_out=2048, T_in=512.
//
// Round 8: r6 compute body; final reduce = 2 atomicAdd(float) per non-empty
// block onto out[b]/out[64+b] (128 addresses, ~32 adds each, no fence --
// r7 showed per-block __threadfence + single-address ticket costs ~170us).
// d_out zeroed per call via a 512 B hipMemsetAsync graph node.

#define GA_B     64
#define GA_TOUT  2048
#define GA_TIN   512
#define ROWS_PER_WAVE   8
#define WAVES_PER_BLOCK 4
#define ROWS_PER_BLOCK  (ROWS_PER_WAVE * WAVES_PER_BLOCK)   // 32
#define BLOCK_THREADS   256
#define GRID_X          (GA_TOUT / ROWS_PER_BLOCK)           // 64
// KS = sqrt(3.125 * log2(e)):  2^(-(KS*z)^2) = exp(-z^2 * 3.125)
#define KS 2.1233046f

__global__ __launch_bounds__(BLOCK_THREADS)
void ga_kernel(const float* __restrict__ att,
               const int* __restrict__ ilens,
               const int* __restrict__ olens,
               float* __restrict__ out) {
    const int b  = blockIdx.y;
    const int ol = olens[b];
    const int rowBase = blockIdx.x * ROWS_PER_BLOCK;
    if (rowBase >= ol) return;                    // whole block invalid

    const int lane = threadIdx.x & 63;
    const int wave = threadIdx.x >> 6;
    const int waveRow = rowBase + wave * ROWS_PER_WAVE;

    const int il = ilens[b];
    const int nv = (il + 3) >> 2;                 // float4 chunks per row

    float l1 = 0.0f, l2 = 0.0f;

    if (waveRow < ol) {
        const float inv_il_s = KS / (float)il;
        const float inv_ol_s = KS / (float)ol;
        const bool  hi       = (nv > 64);
        const float4* __restrict__ base =
            (const float4*)(att + (size_t)b * GA_TOUT * GA_TIN);

        float ys0[4], ys1[4], m0[4], m1[4];
        #pragma unroll
        for (int j = 0; j < 4; ++j) {
            const int y0 = (lane << 2) + j;
            const int y1 = y0 + 256;
            ys0[j] = (float)y0 * inv_il_s;
            ys1[j] = (float)y1 * inv_il_s;
            m0[j]  = (y0 < il) ? 1.0f : 0.0f;
            m1[j]  = (y1 < il) ? 1.0f : 0.0f;
        }

        float4 A0[ROWS_PER_WAVE], A1[ROWS_PER_WAVE];
        #pragma unroll
        for (int r = 0; r < ROWS_PER_WAVE; ++r) {
            A0[r] = make_float4(0.f, 0.f, 0.f, 0.f);
            A1[r] = make_float4(0.f, 0.f, 0.f, 0.f);
            const int x = waveRow + r;
            if (x < ol) {
                const float4* __restrict__ rowp = base + (size_t)x * (GA_TIN / 4);
                if (lane < nv)              A0[r] = rowp[lane];
                if (hi && (lane + 64 < nv)) A1[r] = rowp[lane + 64];
            }
        }

        #pragma unroll
        for (int r = 0; r < ROWS_PER_WAVE; ++r) {
            const int   x   = waveRow + r;
            const float gxs = (float)x * inv_ol_s;
            {
                const float4 a = A0[r];
                #pragma unroll
                for (int j = 0; j < 4; ++j) {
                    const float av = (j == 0) ? a.x : (j == 1) ? a.y
                                   : (j == 2) ? a.z : a.w;
                    const float w  = ys0[j] - gxs;
                    const float E  = exp2f(-w * w);
                    const float q  = av - av * E;       // guided * att
                    const float e  = q * m0[j];
                    l1 += e;
                    l2 += e * e;
                }
            }
            if (hi) {
                const float4 a = A1[r];
                #pragma unroll
                for (int j = 0; j < 4; ++j) {
                    const float av = (j == 0) ? a.x : (j == 1) ? a.y
                                   : (j == 2) ? a.z : a.w;
                    const float w  = ys1[j] - gxs;
                    const float E  = exp2f(-w * w);
                    const float q  = av - av * E;
                    const float e  = q * m1[j];
                    l1 += e;
                    l2 += e * e;
                }
            }
        }
    }

    // ---- block reduce (4 waves) ----
    #pragma unroll
    for (int o = 32; o > 0; o >>= 1) {
        l1 += __shfl_down(l1, o, 64);
        l2 += __shfl_down(l2, o, 64);
    }
    __shared__ float s1[WAVES_PER_BLOCK];
    __shared__ float s2[WAVES_PER_BLOCK];
    if (lane == 0) { s1[wave] = l1; s2[wave] = l2; }
    __syncthreads();
    if (threadIdx.x == 0) {
        const float inv_ol = 1.0f / (float)ol;
        const float b1 = (s1[0] + s1[1] + s1[2] + s1[3]) * inv_ol;
        const float b2 = (s2[0] + s2[1] + s2[2] + s2[3]) * inv_ol;
        atomicAdd(&out[b],        b1);
        atomicAdd(&out[GA_B + b], b2);
    }
}

extern "C" void kernel_launch(void* const* d_in, const int* in_sizes, int n_in,
                              void* d_out, int out_size, void* d_ws, size_t ws_size,
                              hipStream_t stream) {
    const float* att   = (const float*)d_in[0];
    const int*   ilens = (const int*)d_in[1];
    const int*   olens = (const int*)d_in[2];
    float*       out   = (float*)d_out;

    hipMemsetAsync(out, 0, 2 * GA_B * sizeof(float), stream);  // 512 B
    dim3 grid(GRID_X, GA_B);
    ga_kernel<<<grid, BLOCK_THREADS, 0, stream>>>(att, ilens, olens, out);
}

// Round 9
// 30.293 us; speedup vs baseline: 4.8087x; 1.1447x over previous
//
#include <hip/hip_runtime.h>
#include <hip/hip_bf16.h>

// Guided attention loss, two-kernel (r6 structure, r9 tuning).
//   guided(b,x,y) = 1 - exp(-(y/il - x/ol)^2 / (2*sigma^2)),  sigma=0.4
//   out[b]   = sum(guided*att over valid) / ol
//   out[B+b] = sum((guided*att)^2 over valid) / ol
// Shapes fixed: B=64, T_out=2048, T_in=512.
//
// Round 9: 512-thr blocks (8 waves x 8 rows = 64 rows/block, 2048 blocks);
// dead blocks (rowBase >= ol) early-exit; k2 reads only live chunks
// (lane < ceil(ol/64)) so stale partials are never touched.
// Lesson r7/r8: fences + contended atomics lose to a plain 2nd kernel node.

#define GA_B     64
#define GA_TOUT  2048
#define GA_TIN   512
#define ROWS_PER_WAVE   8
#define WAVES_PER_BLOCK 8
#define ROWS_PER_BLOCK  (ROWS_PER_WAVE * WAVES_PER_BLOCK)   // 64
#define BLOCK_THREADS   (WAVES_PER_BLOCK * 64)               // 512
#define GRID_X          (GA_TOUT / ROWS_PER_BLOCK)           // 32
// KS = sqrt(3.125 * log2(e)):  2^(-(KS*z)^2) = exp(-z^2 * 3.125)
#define KS 2.1233046f

__global__ __launch_bounds__(BLOCK_THREADS)
void ga_partial_kernel(const float* __restrict__ att,
                       const int* __restrict__ ilens,
                       const int* __restrict__ olens,
                       float2* __restrict__ part) {
    const int b  = blockIdx.y;
    const int ol = olens[b];
    const int rowBase = blockIdx.x * ROWS_PER_BLOCK;
    if (rowBase >= ol) return;                    // dead block: k2 won't read it

    const int lane = threadIdx.x & 63;
    const int wave = threadIdx.x >> 6;
    const int waveRow = rowBase + wave * ROWS_PER_WAVE;

    const int il = ilens[b];
    const int nv = (il + 3) >> 2;                 // float4 chunks per row

    float l1 = 0.0f, l2 = 0.0f;

    if (waveRow < ol) {
        const float inv_il_s = KS / (float)il;
        const float inv_ol_s = KS / (float)ol;
        const bool  hi       = (nv > 64);
        const float4* __restrict__ base =
            (const float4*)(att + (size_t)b * GA_TOUT * GA_TIN);

        float ys0[4], ys1[4], m0[4], m1[4];
        #pragma unroll
        for (int j = 0; j < 4; ++j) {
            const int y0 = (lane << 2) + j;
            const int y1 = y0 + 256;
            ys0[j] = (float)y0 * inv_il_s;
            ys1[j] = (float)y1 * inv_il_s;
            m0[j]  = (y0 < il) ? 1.0f : 0.0f;
            m1[j]  = (y1 < il) ? 1.0f : 0.0f;
        }

        float4 A0[ROWS_PER_WAVE], A1[ROWS_PER_WAVE];
        #pragma unroll
        for (int r = 0; r < ROWS_PER_WAVE; ++r) {
            A0[r] = make_float4(0.f, 0.f, 0.f, 0.f);
            A1[r] = make_float4(0.f, 0.f, 0.f, 0.f);
            const int x = waveRow + r;
            if (x < ol) {
                const float4* __restrict__ rowp = base + (size_t)x * (GA_TIN / 4);
                if (lane < nv)              A0[r] = rowp[lane];
                if (hi && (lane + 64 < nv)) A1[r] = rowp[lane + 64];
            }
        }

        #pragma unroll
        for (int r = 0; r < ROWS_PER_WAVE; ++r) {
            const int   x   = waveRow + r;
            const float gxs = (float)x * inv_ol_s;
            {
                const float4 a = A0[r];
                #pragma unroll
                for (int j = 0; j < 4; ++j) {
                    const float av = (j == 0) ? a.x : (j == 1) ? a.y
                                   : (j == 2) ? a.z : a.w;
                    const float w  = ys0[j] - gxs;
                    const float E  = exp2f(-w * w);
                    const float q  = av - av * E;       // guided * att
                    const float e  = q * m0[j];
                    l1 += e;
                    l2 += e * e;
                }
            }
            if (hi) {
                const float4 a = A1[r];
                #pragma unroll
                for (int j = 0; j < 4; ++j) {
                    const float av = (j == 0) ? a.x : (j == 1) ? a.y
                                   : (j == 2) ? a.z : a.w;
                    const float w  = ys1[j] - gxs;
                    const float E  = exp2f(-w * w);
                    const float q  = av - av * E;
                    const float e  = q * m1[j];
                    l1 += e;
                    l2 += e * e;
                }
            }
        }
    }

    // ---- block reduce (8 waves) ----
    #pragma unroll
    for (int o = 32; o > 0; o >>= 1) {
        l1 += __shfl_down(l1, o, 64);
        l2 += __shfl_down(l2, o, 64);
    }
    __shared__ float s1[WAVES_PER_BLOCK];
    __shared__ float s2[WAVES_PER_BLOCK];
    if (lane == 0) { s1[wave] = l1; s2[wave] = l2; }
    __syncthreads();
    if (threadIdx.x == 0) {
        float b1 = 0.f, b2 = 0.f;
        #pragma unroll
        for (int w = 0; w < WAVES_PER_BLOCK; ++w) { b1 += s1[w]; b2 += s2[w]; }
        part[b * GRID_X + blockIdx.x] = make_float2(b1, b2);
    }
}

__global__ __launch_bounds__(64)
void ga_final_kernel(const float2* __restrict__ part,
                     const int* __restrict__ olens,
                     float* __restrict__ out) {
    const int b  = blockIdx.x;
    const int t  = threadIdx.x;
    const int ol = olens[b];
    const int nchunks = (ol + ROWS_PER_BLOCK - 1) / ROWS_PER_BLOCK;  // <= 32
    float l1 = 0.0f, l2 = 0.0f;
    if (t < nchunks) {
        const float2 p = part[b * GRID_X + t];
        l1 = p.x; l2 = p.y;
    }
    #pragma unroll
    for (int o = 32; o > 0; o >>= 1) {
        l1 += __shfl_down(l1, o, 64);
        l2 += __shfl_down(l2, o, 64);
    }
    if (t == 0) {
        const float d = (float)ol;
        out[b]        = l1 / d;
        out[GA_B + b] = l2 / d;
    }
}

extern "C" void kernel_launch(void* const* d_in, const int* in_sizes, int n_in,
                              void* d_out, int out_size, void* d_ws, size_t ws_size,
                              hipStream_t stream) {
    const float* att   = (const float*)d_in[0];
    const int*   ilens = (const int*)d_in[1];
    const int*   olens = (const int*)d_in[2];
    float*       out   = (float*)d_out;
    float2*      part  = (float2*)d_ws;   // 64 * 32 * 8 B = 16 KB

    dim3 grid1(GRID_X, GA_B);
    ga_partial_kernel<<<grid1, BLOCK_THREADS, 0, stream>>>(att, ilens, olens, part);
    ga_final_kernel<<<GA_B, 64, 0, stream>>>(part, olens, out);
}

// Round 10
// 22.250 us; speedup vs baseline: 6.5469x; 1.3615x over previous
//
#include <hip/hip_runtime.h>
#include <hip/hip_bf16.h>

// Guided attention loss, two-kernel (r6 geometry, r10 window-skip compute).
//   guided(b,x,y) = 1 - exp(-(y/il - x/ol)^2 / (2*sigma^2)),  sigma=0.4
//   out[b]   = sum(guided*att over valid) / ol
//   out[B+b] = sum((guided*att)^2 over valid) / ol
// Shapes fixed: B=64, T_out=2048, T_in=512.
//
// Round 10: 64-column windows. lane = q*16+l: 16-lane group l covers a
// 64-col window of row (waveRow + g*4 + q). Window loop bound ceil(il/64)
// is wave-uniform -> scalar-branch skip of dead loads+compute; windows
// fully below il need no column mask (5 VALU + 1 trans / element); only
// the boundary window masks. Rows beyond ol contribute 0 via zeroed loads.
// Geometry kept from r6 (best: 4096 x 256-thr blocks, always-write parts).

#define GA_B     64
#define GA_TOUT  2048
#define GA_TIN   512
#define ROWS_PER_WAVE   8
#define WAVES_PER_BLOCK 4
#define ROWS_PER_BLOCK  (ROWS_PER_WAVE * WAVES_PER_BLOCK)   // 32
#define BLOCK_THREADS   256
#define GRID_X          (GA_TOUT / ROWS_PER_BLOCK)           // 64
// KS = sqrt(3.125 * log2(e)):  2^(-(KS*z)^2) = exp(-z^2 * 3.125)
#define KS 2.1233046f

__global__ __launch_bounds__(BLOCK_THREADS)
void ga_partial_kernel(const float* __restrict__ att,
                       const int* __restrict__ ilens,
                       const int* __restrict__ olens,
                       float2* __restrict__ part) {
    const int b    = blockIdx.y;
    const int lane = threadIdx.x & 63;
    const int wave = threadIdx.x >> 6;
    const int waveRow = blockIdx.x * ROWS_PER_BLOCK + wave * ROWS_PER_WAVE;

    const int ol = olens[b];
    const int il = ilens[b];

    float l1 = 0.0f, l2 = 0.0f;

    if (waveRow < ol) {
        const int q = lane >> 4;                 // row within 4-row group
        const int l = lane & 15;                 // column sub-group
        const int full_w = il >> 6;              // windows with all 64 cols valid
        const int nw     = (il + 63) >> 6;       // total windows incl. boundary

        const float inv_il_s = KS / (float)il;
        const float inv_ol_s = KS / (float)ol;
        const float* __restrict__ bbase = att + (size_t)b * GA_TOUT * GA_TIN;

        int   row[2];
        float gx[2];
        #pragma unroll
        for (int g = 0; g < 2; ++g) {
            row[g] = waveRow + g * 4 + q;
            gx[g]  = (float)row[g] * inv_ol_s;
        }

        float ysb[4];
        #pragma unroll
        for (int j = 0; j < 4; ++j)
            ysb[j] = (float)((l << 2) + j) * inv_il_s;

        // boundary-window column masks (window index full_w)
        float mb[4];
        #pragma unroll
        for (int j = 0; j < 4; ++j) {
            const int col = (full_w << 6) + (l << 2) + j;
            mb[j] = (col < il) ? 1.0f : 0.0f;
        }

        // ---- loads: up to 16 float4 issued before compute ----
        float4 A[2][8];
        #pragma unroll
        for (int w = 0; w < 8; ++w) {
            #pragma unroll
            for (int g = 0; g < 2; ++g) {
                A[g][w] = make_float4(0.f, 0.f, 0.f, 0.f);
                if (w < nw && row[g] < ol) {
                    A[g][w] = ((const float4*)(bbase + (size_t)row[g] * GA_TIN))
                              [(w << 4) + l];
                }
            }
        }

        // ---- compute: full windows unmasked, boundary window masked ----
        #pragma unroll
        for (int w = 0; w < 8; ++w) {
            if (w < full_w) {                       // wave-uniform branch
                const float off = (float)(w << 6) * inv_il_s;
                #pragma unroll
                for (int g = 0; g < 2; ++g) {
                    const float  c = off - gx[g];
                    const float4 a = A[g][w];
                    #pragma unroll
                    for (int j = 0; j < 4; ++j) {
                        const float av = (j == 0) ? a.x : (j == 1) ? a.y
                                       : (j == 2) ? a.z : a.w;
                        const float wv = ysb[j] + c;
                        const float E  = exp2f(-wv * wv);
                        const float e  = av - av * E;   // row>=ol -> av=0 -> e=0
                        l1 += e;
                        l2 += e * e;
                    }
                }
            } else if (w < nw) {                    // boundary window
                const float off = (float)(w << 6) * inv_il_s;
                #pragma unroll
                for (int g = 0; g < 2; ++g) {
                    const float  c = off - gx[g];
                    const float4 a = A[g][w];
                    #pragma unroll
                    for (int j = 0; j < 4; ++j) {
                        const float av = (j == 0) ? a.x : (j == 1) ? a.y
                                       : (j == 2) ? a.z : a.w;
                        const float wv = ysb[j] + c;
                        const float E  = exp2f(-wv * wv);
                        const float e  = (av - av * E) * mb[j];
                        l1 += e;
                        l2 += e * e;
                    }
                }
            }
        }
    }

    // ---- block reduce (4 waves); ALWAYS write so k2 may read every chunk ----
    #pragma unroll
    for (int o = 32; o > 0; o >>= 1) {
        l1 += __shfl_down(l1, o, 64);
        l2 += __shfl_down(l2, o, 64);
    }
    __shared__ float s1[WAVES_PER_BLOCK];
    __shared__ float s2[WAVES_PER_BLOCK];
    if (lane == 0) { s1[wave] = l1; s2[wave] = l2; }
    __syncthreads();
    if (threadIdx.x == 0) {
        const float b1 = s1[0] + s1[1] + s1[2] + s1[3];
        const float b2 = s2[0] + s2[1] + s2[2] + s2[3];
        part[b * GRID_X + blockIdx.x] = make_float2(b1, b2);
    }
}

__global__ __launch_bounds__(64)
void ga_final_kernel(const float2* __restrict__ part,
                     const int* __restrict__ olens,
                     float* __restrict__ out) {
    const int b = blockIdx.x;
    const int t = threadIdx.x;
    const float2 p = part[b * GRID_X + t];   // exactly 64 chunks per batch
    float l1 = p.x, l2 = p.y;
    #pragma unroll
    for (int o = 32; o > 0; o >>= 1) {
        l1 += __shfl_down(l1, o, 64);
        l2 += __shfl_down(l2, o, 64);
    }
    if (t == 0) {
        const float d = (float)olens[b];
        out[b]        = l1 / d;
        out[GA_B + b] = l2 / d;
    }
}

extern "C" void kernel_launch(void* const* d_in, const int* in_sizes, int n_in,
                              void* d_out, int out_size, void* d_ws, size_t ws_size,
                              hipStream_t stream) {
    const float* att   = (const float*)d_in[0];
    const int*   ilens = (const int*)d_in[1];
    const int*   olens = (const int*)d_in[2];
    float*       out   = (float*)d_out;
    float2*      part  = (float2*)d_ws;   // 64 * 64 * 8 B = 32 KB

    dim3 grid1(GRID_X, GA_B);
    ga_partial_kernel<<<grid1, BLOCK_THREADS, 0, stream>>>(att, ilens, olens, part);
    ga_final_kernel<<<GA_B, 64, 0, stream>>>(part, olens, out);
}